// Round 3
// baseline (169.955 us; speedup 1.0000x reference)
//
#include <hip/hip_runtime.h>
#include <hip/hip_bf16.h>
#include <stdint.h>

#define T_TOKENS 8192
#define D_DIM 1024
#define H_DIM 2048
#define N_EXPERTS 8

typedef __attribute__((ext_vector_type(8))) short bf16x8;
typedef __attribute__((ext_vector_type(8))) unsigned short u16x8;
typedef __attribute__((ext_vector_type(4))) float f32x4;

typedef __attribute__((address_space(1))) const void* gptr_t;
typedef __attribute__((address_space(3))) void* lptr_t;

__device__ __forceinline__ unsigned short f2bf(float f) {
  union { float f; unsigned int u; } x; x.f = f;
  unsigned int r = x.u + 0x7FFFu + ((x.u >> 16) & 1u);
  return (unsigned short)(r >> 16);
}
__device__ __forceinline__ float bf2f(unsigned short b) {
  union { unsigned int u; float f; } x; x.u = ((unsigned int)b) << 16;
  return x.f;
}

__device__ __forceinline__ void gload16(const void* g, void* l) {
  __builtin_amdgcn_global_load_lds((gptr_t)g, (lptr_t)l, 16, 0, 0);
}

// Sync discipline (rule #18: sched_barrier after inline-asm waits / raw barriers)
#define SBAR()  do { __builtin_amdgcn_s_barrier(); __builtin_amdgcn_sched_barrier(0); } while (0)
#define LGKM0() do { asm volatile("s_waitcnt lgkmcnt(0)" ::: "memory"); __builtin_amdgcn_sched_barrier(0); } while (0)
#define VMW(n)  do { __builtin_amdgcn_sched_barrier(0); asm volatile("s_waitcnt vmcnt(" #n ")" ::: "memory"); } while (0)

// ---------------------------------------------------------------------------
// Fused fp32 -> bf16 conversion (8 floats / iter, 16B stores).
// ---------------------------------------------------------------------------
__global__ void cvt_all(const float* __restrict__ x, const float* __restrict__ wu,
                        const float* __restrict__ wd,
                        unsigned short* __restrict__ xb, unsigned short* __restrict__ wub,
                        unsigned short* __restrict__ wdb) {
  const int NX = T_TOKENS * D_DIM / 8;
  const int NW = N_EXPERTS * H_DIM * D_DIM / 8;
  const int total = NX + 2 * NW;
  for (int i = blockIdx.x * blockDim.x + threadIdx.x; i < total; i += gridDim.x * blockDim.x) {
    const float* src; unsigned short* dst; int off;
    if (i < NX)            { src = x;  dst = xb;  off = i; }
    else if (i < NX + NW)  { src = wu; dst = wub; off = i - NX; }
    else                   { src = wd; dst = wdb; off = i - NX - NW; }
    const float4 v0 = *reinterpret_cast<const float4*>(src + (size_t)off * 8);
    const float4 v1 = *reinterpret_cast<const float4*>(src + (size_t)off * 8 + 4);
    u16x8 o;
    o[0] = f2bf(v0.x); o[1] = f2bf(v0.y); o[2] = f2bf(v0.z); o[3] = f2bf(v0.w);
    o[4] = f2bf(v1.x); o[5] = f2bf(v1.y); o[6] = f2bf(v1.z); o[7] = f2bf(v1.w);
    *reinterpret_cast<u16x8*>(dst + (size_t)off * 8) = o;
  }
}

// ---------------------------------------------------------------------------
// GEMM1: hsq[T,H] = bf16(relu(bf16(x @ w_up^T))^2), grouped by expert rows.
// BM=256 BN=256 BK=64, 8 waves 2Mx4N, 4 phases/K-tile. LDS: 4 K-half slots
// per operand, [256][32] bf16. XOR swizzle (T2, rule #21): LDS cell (R,cb)
// holds global granule cb ^ ((R>>1)&3); staging pre-swizzles the GLOBAL col,
// LDS dest stays linear; reads use per-lane-constant swizzled block.
// ---------------------------------------------------------------------------
__global__ __launch_bounds__(512, 2)
void gg1_up(const unsigned short* __restrict__ A,  // (T, D) bf16
            const unsigned short* __restrict__ B,  // (E, H, D) bf16
            const int* __restrict__ counts,
            unsigned short* __restrict__ O) {      // (T, H) bf16
  constexpr int K = D_DIM;
  constexpr int NT = K / 64;  // 16
  __shared__ short lA[4 * 8192];
  __shared__ short lB[4 * 8192];

  const int tid = threadIdx.x;
  const int wid = tid >> 6, lane = tid & 63;
  const int wr = wid >> 2, wc = wid & 3;
  const int bid = blockIdx.x;
  const int cb = bid & 7, rb = bid >> 3;  // T1: XCD k owns column panel k
  const int r0 = rb * 256, c0 = cb * 256;

  int csum[N_EXPERTS + 1];
  csum[0] = 0;
  for (int e = 0; e < N_EXPERTS; ++e) csum[e + 1] = csum[e] + counts[e];
  int eLo = 0;
  while (eLo < N_EXPERTS - 1 && csum[eLo + 1] <= r0) ++eLo;
  int eHi = eLo;
  while (eHi < N_EXPERTS - 1 && csum[eHi + 1] < r0 + 256) ++eHi;

  // staging: lane -> row (lane>>2), swizzled 16B-granule ((lane&3)^((lane>>3)&3))
  const int srow = lane >> 2;
  const int scol = ((lane & 3) ^ ((lane >> 3) & 3)) * 8;
  const size_t aBase = (size_t)(r0 + wid * 16 + srow) * K + scol;
  const size_t bBase0 = (size_t)(c0 + wid * 16 + srow) * K + scol;
  const int ldsW = wid * 512;
  const int l15 = lane & 15;
  const int l4 = ((lane >> 4) ^ ((lane >> 1) & 3)) * 8;  // swizzled read granule

  for (int e = eLo; e <= eHi; ++e) {
    const unsigned short* Be = B + (size_t)e * H_DIM * K;
    f32x4 acc[8][4];
#pragma unroll
    for (int mi = 0; mi < 8; ++mi)
#pragma unroll
      for (int ni = 0; ni < 4; ++ni) acc[mi][ni] = (f32x4){0.f, 0.f, 0.f, 0.f};

#define STAGE_A1(t, h) do { const int s_ = (((t) & 1) << 1) | (h); \
    gload16(A + aBase + (size_t)(t) * 64 + (h) * 32,                 &lA[s_ * 8192 + ldsW]); \
    gload16(A + aBase + (size_t)128 * K + (size_t)(t) * 64 + (h) * 32, &lA[s_ * 8192 + ldsW + 4096]); } while (0)
#define STAGE_B1(t, h) do { const int s_ = (((t) & 1) << 1) | (h); \
    gload16(Be + bBase0 + (size_t)(t) * 64 + (h) * 32,                 &lB[s_ * 8192 + ldsW]); \
    gload16(Be + bBase0 + (size_t)128 * K + (size_t)(t) * 64 + (h) * 32, &lB[s_ * 8192 + ldsW + 4096]); } while (0)
#define G1_RD(MH, SLOT) do { \
    _Pragma("unroll") for (int m_ = 0; m_ < 4; ++m_) \
      fa[m_] = *(const bf16x8*)&lA[(SLOT) * 8192 + (wr * 128 + (MH) * 64 + m_ * 16 + l15) * 32 + l4]; \
    _Pragma("unroll") for (int n_ = 0; n_ < 4; ++n_) \
      fb[n_] = *(const bf16x8*)&lB[(SLOT) * 8192 + (wc * 64 + n_ * 16 + l15) * 32 + l4]; \
  } while (0)
#define G1_MM(MH) do { \
    __builtin_amdgcn_s_setprio(1); \
    _Pragma("unroll") for (int m_ = 0; m_ < 4; ++m_) \
      _Pragma("unroll") for (int n_ = 0; n_ < 4; ++n_) \
        acc[(MH) * 4 + m_][n_] = __builtin_amdgcn_mfma_f32_16x16x32_bf16(fa[m_], fb[n_], acc[(MH) * 4 + m_][n_], 0, 0, 0); \
    __builtin_amdgcn_s_setprio(0); \
  } while (0)

    STAGE_A1(0, 0); STAGE_B1(0, 0); STAGE_A1(0, 1); STAGE_B1(0, 1);
    STAGE_A1(1, 0); STAGE_B1(1, 0);
    VMW(8); SBAR();

#pragma unroll 1
    for (int t = 0; t < NT - 2; ++t) {
      const int k0 = ((t & 1) << 1), k1 = k0 | 1;
      { bf16x8 fa[4], fb[4]; G1_RD(0, k0); STAGE_A1(t + 1, 1);          LGKM0(); G1_MM(0); SBAR(); }
      { bf16x8 fa[4], fb[4]; G1_RD(1, k0); STAGE_B1(t + 1, 1); VMW(8);  LGKM0(); G1_MM(1); SBAR(); }
      { bf16x8 fa[4], fb[4]; G1_RD(0, k1); STAGE_A1(t + 2, 0);          LGKM0(); G1_MM(0); SBAR(); }
      { bf16x8 fa[4], fb[4]; G1_RD(1, k1); STAGE_B1(t + 2, 0); VMW(8);  LGKM0(); G1_MM(1); SBAR(); }
    }
    {  // t = NT-2
      const int k0 = (((NT - 2) & 1) << 1), k1 = k0 | 1;
      { bf16x8 fa[4], fb[4]; G1_RD(0, k0); STAGE_A1(NT - 1, 1);         LGKM0(); G1_MM(0); SBAR(); }
      { bf16x8 fa[4], fb[4]; G1_RD(1, k0); STAGE_B1(NT - 1, 1); VMW(8); LGKM0(); G1_MM(1); SBAR(); }
      { bf16x8 fa[4], fb[4]; G1_RD(0, k1);                              LGKM0(); G1_MM(0); SBAR(); }
      { bf16x8 fa[4], fb[4]; G1_RD(1, k1);                     VMW(4);  LGKM0(); G1_MM(1); SBAR(); }
    }
    {  // t = NT-1
      const int k0 = (((NT - 1) & 1) << 1), k1 = k0 | 1;
      { bf16x8 fa[4], fb[4]; G1_RD(0, k0);                              LGKM0(); G1_MM(0); SBAR(); }
      { bf16x8 fa[4], fb[4]; G1_RD(1, k0);                     VMW(0);  LGKM0(); G1_MM(1); SBAR(); }
      { bf16x8 fa[4], fb[4]; G1_RD(0, k1);                              LGKM0(); G1_MM(0); SBAR(); }
      { bf16x8 fa[4], fb[4]; G1_RD(1, k1);                              LGKM0(); G1_MM(1); SBAR(); }
    }

    // epilogue: C/D layout col=lane&15, row=(lane>>4)*4+reg
    const int segLo = csum[e], segHi = csum[e + 1];
#pragma unroll
    for (int mi = 0; mi < 8; ++mi) {
      const int rowb = r0 + wr * 128 + mi * 16 + ((lane >> 4) << 2);
#pragma unroll
      for (int ni = 0; ni < 4; ++ni) {
        const int col = c0 + wc * 64 + ni * 16 + l15;
#pragma unroll
        for (int r = 0; r < 4; ++r) {
          const int gr = rowb + r;
          if (gr >= segLo && gr < segHi) {
            float h = bf2f(f2bf(acc[mi][ni][r]));
            h = h > 0.f ? h : 0.f;
            O[(size_t)gr * H_DIM + col] = f2bf(h * h);
          }
        }
      }
    }
#undef STAGE_A1
#undef STAGE_B1
#undef G1_RD
#undef G1_MM
  }
}

// ---------------------------------------------------------------------------
// GEMM2: out[T,D] = fp32(bf16(hsq @ w_down^T)), grouped.
// BM=256 BN=128 BK=64, 8 waves 4Mx2N, 2 phases/K-tile. Same XOR swizzle.
// ---------------------------------------------------------------------------
__global__ __launch_bounds__(512, 2)
void gg2_down(const unsigned short* __restrict__ A,  // (T, H) bf16
              const unsigned short* __restrict__ B,  // (E, D, H) bf16
              const int* __restrict__ counts,
              float* __restrict__ O) {               // (T, D) fp32
  constexpr int K = H_DIM;
  constexpr int NT = K / 64;  // 32
  __shared__ short lA[4 * 8192];
  __shared__ short lB[4 * 4096];

  const int tid = threadIdx.x;
  const int wid = tid >> 6, lane = tid & 63;
  const int wr = wid >> 1, wc = wid & 1;
  const int bid = blockIdx.x;
  const int cb = bid & 7, rb = bid >> 3;
  const int r0 = rb * 256, c0 = cb * 128;

  int csum[N_EXPERTS + 1];
  csum[0] = 0;
  for (int e = 0; e < N_EXPERTS; ++e) csum[e + 1] = csum[e] + counts[e];
  int eLo = 0;
  while (eLo < N_EXPERTS - 1 && csum[eLo + 1] <= r0) ++eLo;
  int eHi = eLo;
  while (eHi < N_EXPERTS - 1 && csum[eHi + 1] < r0 + 256) ++eHi;

  const int srow = lane >> 2;
  const int scol = ((lane & 3) ^ ((lane >> 3) & 3)) * 8;
  const size_t aBase = (size_t)(r0 + wid * 16 + srow) * K + scol;
  const size_t bBase0 = (size_t)(c0 + wid * 16 + srow) * K + scol;
  const int ldsW = wid * 512;
  const int l15 = lane & 15;
  const int l4 = ((lane >> 4) ^ ((lane >> 1) & 3)) * 8;

  for (int e = eLo; e <= eHi; ++e) {
    const unsigned short* Be = B + (size_t)e * D_DIM * K;
    f32x4 acc[4][4];
#pragma unroll
    for (int mi = 0; mi < 4; ++mi)
#pragma unroll
      for (int ni = 0; ni < 4; ++ni) acc[mi][ni] = (f32x4){0.f, 0.f, 0.f, 0.f};

#define STAGE_A2(t, h) do { const int s_ = (((t) & 1) << 1) | (h); \
    gload16(A + aBase + (size_t)(t) * 64 + (h) * 32,                 &lA[s_ * 8192 + ldsW]); \
    gload16(A + aBase + (size_t)128 * K + (size_t)(t) * 64 + (h) * 32, &lA[s_ * 8192 + ldsW + 4096]); } while (0)
#define STAGE_B2(t, h) do { const int s_ = (((t) & 1) << 1) | (h); \
    gload16(Be + bBase0 + (size_t)(t) * 64 + (h) * 32, &lB[s_ * 4096 + ldsW]); } while (0)
#define G2_RD(SLOT) do { \
    _Pragma("unroll") for (int m_ = 0; m_ < 4; ++m_) \
      fa[m_] = *(const bf16x8*)&lA[(SLOT) * 8192 + (wr * 64 + m_ * 16 + l15) * 32 + l4]; \
    _Pragma("unroll") for (int n_ = 0; n_ < 4; ++n_) \
      fb[n_] = *(const bf16x8*)&lB[(SLOT) * 4096 + (wc * 64 + n_ * 16 + l15) * 32 + l4]; \
  } while (0)
#define G2_MM() do { \
    __builtin_amdgcn_s_setprio(1); \
    _Pragma("unroll") for (int m_ = 0; m_ < 4; ++m_) \
      _Pragma("unroll") for (int n_ = 0; n_ < 4; ++n_) \
        acc[m_][n_] = __builtin_amdgcn_mfma_f32_16x16x32_bf16(fa[m_], fb[n_], acc[m_][n_], 0, 0, 0); \
    __builtin_amdgcn_s_setprio(0); \
  } while (0)

    STAGE_A2(0, 0); STAGE_B2(0, 0); STAGE_A2(0, 1); STAGE_B2(0, 1);
    STAGE_A2(1, 0); STAGE_B2(1, 0);
    VMW(6); SBAR();

#pragma unroll 1
    for (int t = 0; t < NT - 2; ++t) {
      const int k0 = ((t & 1) << 1), k1 = k0 | 1;
      { bf16x8 fa[4], fb[4]; G2_RD(k0); STAGE_A2(t + 1, 1); STAGE_B2(t + 1, 1); VMW(6); LGKM0(); G2_MM(); SBAR(); }
      { bf16x8 fa[4], fb[4]; G2_RD(k1); STAGE_A2(t + 2, 0); STAGE_B2(t + 2, 0); VMW(6); LGKM0(); G2_MM(); SBAR(); }
    }
    {  // t = NT-2
      const int k0 = (((NT - 2) & 1) << 1), k1 = k0 | 1;
      { bf16x8 fa[4], fb[4]; G2_RD(k0); STAGE_A2(NT - 1, 1); STAGE_B2(NT - 1, 1); VMW(6); LGKM0(); G2_MM(); SBAR(); }
      { bf16x8 fa[4], fb[4]; G2_RD(k1);                                          VMW(3); LGKM0(); G2_MM(); SBAR(); }
    }
    {  // t = NT-1
      const int k0 = (((NT - 1) & 1) << 1), k1 = k0 | 1;
      { bf16x8 fa[4], fb[4]; G2_RD(k0);                                          VMW(0); LGKM0(); G2_MM(); SBAR(); }
      { bf16x8 fa[4], fb[4]; G2_RD(k1);                                                  LGKM0(); G2_MM(); SBAR(); }
    }

    const int segLo = csum[e], segHi = csum[e + 1];
#pragma unroll
    for (int mi = 0; mi < 4; ++mi) {
      const int rowb = r0 + wr * 64 + mi * 16 + ((lane >> 4) << 2);
#pragma unroll
      for (int ni = 0; ni < 4; ++ni) {
        const int col = c0 + wc * 64 + ni * 16 + l15;
#pragma unroll
        for (int r = 0; r < 4; ++r) {
          const int gr = rowb + r;
          if (gr >= segLo && gr < segHi) {
            O[(size_t)gr * D_DIM + col] = bf2f(f2bf(acc[mi][ni][r]));
          }
        }
      }
    }
#undef STAGE_A2
#undef STAGE_B2
#undef G2_RD
#undef G2_MM
  }
}

extern "C" void kernel_launch(void* const* d_in, const int* in_sizes, int n_in,
                              void* d_out, int out_size, void* d_ws, size_t ws_size,
                              hipStream_t stream) {
  const float* x = (const float*)d_in[0];
  const float* w_up = (const float*)d_in[1];
  const float* w_down = (const float*)d_in[2];
  const int* counts = (const int*)d_in[3];
  float* out = (float*)d_out;

  char* ws = (char*)d_ws;
  unsigned short* xb  = (unsigned short*)(ws);
  unsigned short* wub = (unsigned short*)(ws + (size_t)16 * 1024 * 1024);
  unsigned short* wdb = (unsigned short*)(ws + (size_t)48 * 1024 * 1024);
  unsigned short* hsq = (unsigned short*)(ws + (size_t)80 * 1024 * 1024);

  cvt_all<<<2048, 256, 0, stream>>>(x, w_up, w_down, xb, wub, wdb);
  gg1_up<<<256, 512, 0, stream>>>(xb, wub, counts, hsq);
  gg2_down<<<256, 512, 0, stream>>>(hsq, wdb, counts, out);
}

// Round 4
// 140.030 us; speedup vs baseline: 1.2137x; 1.2137x over previous
//
#include <hip/hip_runtime.h>
#include <hip/hip_bf16.h>
#include <stdint.h>

#define T_TOKENS 8192
#define D_DIM 1024
#define H_DIM 2048
#define N_EXPERTS 8

typedef __attribute__((ext_vector_type(8))) short bf16x8;
typedef __attribute__((ext_vector_type(8))) unsigned short u16x8;
typedef __attribute__((ext_vector_type(4))) float f32x4;

typedef __attribute__((address_space(1))) const void* gptr_t;
typedef __attribute__((address_space(3))) void* lptr_t;

__device__ __forceinline__ unsigned short f2bf(float f) {
  union { float f; unsigned int u; } x; x.f = f;
  unsigned int r = x.u + 0x7FFFu + ((x.u >> 16) & 1u);
  return (unsigned short)(r >> 16);
}
__device__ __forceinline__ float bf2f(unsigned short b) {
  union { unsigned int u; float f; } x; x.u = ((unsigned int)b) << 16;
  return x.f;
}

__device__ __forceinline__ void gload16(const void* g, void* l) {
  __builtin_amdgcn_global_load_lds((gptr_t)g, (lptr_t)l, 16, 0, 0);
}

// Sync discipline (rule #18: sched_barrier after inline-asm waits / raw barriers)
#define SBAR()  do { __builtin_amdgcn_s_barrier(); __builtin_amdgcn_sched_barrier(0); } while (0)
#define LGKM0() do { asm volatile("s_waitcnt lgkmcnt(0)" ::: "memory"); __builtin_amdgcn_sched_barrier(0); } while (0)
#define VMW(n)  do { __builtin_amdgcn_sched_barrier(0); asm volatile("s_waitcnt vmcnt(" #n ")" ::: "memory"); } while (0)

// ---------------------------------------------------------------------------
// fp32 -> bf16 conversion. Block-region partitioning: each block copies one
// contiguous 8KB-per-wavefront chunk of ONE array (pure stream, no per-iter
// branch, no grid-stride). Round-1 measured pure streams at ~36us vs 74us
// for the grid-stride 3-way-branch fusion.
//   blocks [0,4096)        -> x      (8192*1024 elems)
//   blocks [4096,12288)    -> w_up   (8*2048*1024)
//   blocks [12288,20480)   -> w_down (8*1024*2048)
// Each thread: 8 floats (32B read, 16B write), exact coverage, no guard.
// ---------------------------------------------------------------------------
__global__ void cvt_region(const float* __restrict__ x, const float* __restrict__ wu,
                           const float* __restrict__ wd,
                           unsigned short* __restrict__ xb, unsigned short* __restrict__ wub,
                           unsigned short* __restrict__ wdb) {
  const int b = blockIdx.x;
  const float* src; unsigned short* dst; int rb;
  if (b < 4096)        { src = x;  dst = xb;  rb = b; }
  else if (b < 12288)  { src = wu; dst = wub; rb = b - 4096; }
  else                 { src = wd; dst = wdb; rb = b - 12288; }
  const size_t off = ((size_t)rb * 256 + threadIdx.x) * 8;
  const float4 v0 = *reinterpret_cast<const float4*>(src + off);
  const float4 v1 = *reinterpret_cast<const float4*>(src + off + 4);
  u16x8 o;
  o[0] = f2bf(v0.x); o[1] = f2bf(v0.y); o[2] = f2bf(v0.z); o[3] = f2bf(v0.w);
  o[4] = f2bf(v1.x); o[5] = f2bf(v1.y); o[6] = f2bf(v1.z); o[7] = f2bf(v1.w);
  *reinterpret_cast<u16x8*>(dst + off) = o;
}

// ---------------------------------------------------------------------------
// Grouped GEMM, clone of the measured-fast gg2 structure for BOTH matmuls:
// C[M,N] = A[M,K] @ B[e][N,K]^T over expert row segments.
// BM=256 BN=128 BK=64. 8 waves 4Mx2N (per-wave 64x64, acc[4][4]).
// 2 phases per K-tile (K-half each), counted vmcnt(6) every phase (2 K-halves
// in flight), one s_barrier per phase, setprio around the 16-MFMA cluster.
// LDS: 4 K-half slots per operand: lA 4x[256][32] (64KB) + lB 4x[128][32]
// (32KB) = 96KB -> 1 block/CU. XOR-swizzled granules (conflict-free, rule #21:
// pre-swizzled GLOBAL source + linear LDS dest + swizzled read).
// FUSE=true: O=bf16(relu(bf16(acc))^2) -> OB. FUSE=false: O=f32(bf16(acc)) -> OF.
// ---------------------------------------------------------------------------
template <int K, int N, bool FUSE>
__global__ __launch_bounds__(512, 2)
void ggemm(const unsigned short* __restrict__ A,
           const unsigned short* __restrict__ B,
           const int* __restrict__ counts,
           unsigned short* __restrict__ OB,
           float* __restrict__ OF) {
  constexpr int NT = K / 64;
  constexpr int NCB = N / 128;  // column panels
  __shared__ short lA[4 * 8192];
  __shared__ short lB[4 * 4096];

  const int tid = threadIdx.x;
  const int wid = tid >> 6, lane = tid & 63;
  const int wr = wid >> 1, wc = wid & 1;
  const int bid = blockIdx.x;
  const int cb = bid % NCB, rb = bid / NCB;  // same-cb blocks share an XCD (NCB%8==0)
  const int r0 = rb * 256, c0 = cb * 128;

  int csum[N_EXPERTS + 1];
  csum[0] = 0;
  for (int e = 0; e < N_EXPERTS; ++e) csum[e + 1] = csum[e] + counts[e];
  int eLo = 0;
  while (eLo < N_EXPERTS - 1 && csum[eLo + 1] <= r0) ++eLo;
  int eHi = eLo;
  while (eHi < N_EXPERTS - 1 && csum[eHi + 1] < r0 + 256) ++eHi;

  // staging: lane -> row (lane>>2), XOR-swizzled 16B granule (rule #21: swizzle
  // the GLOBAL source, LDS dest linear)
  const int srow = lane >> 2;
  const int scol = ((lane & 3) ^ ((lane >> 3) & 3)) * 8;
  const size_t aBase = (size_t)(r0 + wid * 16 + srow) * K + scol;
  const size_t bBase0 = (size_t)(c0 + wid * 16 + srow) * K + scol;
  const int ldsW = wid * 512;
  const int l15 = lane & 15;
  const int l4 = ((lane >> 4) ^ ((lane >> 1) & 3)) * 8;  // swizzled read granule

  for (int e = eLo; e <= eHi; ++e) {
    const unsigned short* Be = B + (size_t)e * N * K;
    f32x4 acc[4][4];
#pragma unroll
    for (int mi = 0; mi < 4; ++mi)
#pragma unroll
      for (int ni = 0; ni < 4; ++ni) acc[mi][ni] = (f32x4){0.f, 0.f, 0.f, 0.f};

#define STAGE_A(t, h) do { const int s_ = (((t) & 1) << 1) | (h); \
    gload16(A + aBase + (size_t)(t) * 64 + (h) * 32,                 &lA[s_ * 8192 + ldsW]); \
    gload16(A + aBase + (size_t)128 * K + (size_t)(t) * 64 + (h) * 32, &lA[s_ * 8192 + ldsW + 4096]); } while (0)
#define STAGE_B(t, h) do { const int s_ = (((t) & 1) << 1) | (h); \
    gload16(Be + bBase0 + (size_t)(t) * 64 + (h) * 32, &lB[s_ * 4096 + ldsW]); } while (0)
#define G_RD(SLOT) do { \
    _Pragma("unroll") for (int m_ = 0; m_ < 4; ++m_) \
      fa[m_] = *(const bf16x8*)&lA[(SLOT) * 8192 + (wr * 64 + m_ * 16 + l15) * 32 + l4]; \
    _Pragma("unroll") for (int n_ = 0; n_ < 4; ++n_) \
      fb[n_] = *(const bf16x8*)&lB[(SLOT) * 4096 + (wc * 64 + n_ * 16 + l15) * 32 + l4]; \
  } while (0)
#define G_MM() do { \
    __builtin_amdgcn_s_setprio(1); \
    _Pragma("unroll") for (int m_ = 0; m_ < 4; ++m_) \
      _Pragma("unroll") for (int n_ = 0; n_ < 4; ++n_) \
        acc[m_][n_] = __builtin_amdgcn_mfma_f32_16x16x32_bf16(fa[m_], fb[n_], acc[m_][n_], 0, 0, 0); \
    __builtin_amdgcn_s_setprio(0); \
  } while (0)

    STAGE_A(0, 0); STAGE_B(0, 0); STAGE_A(0, 1); STAGE_B(0, 1);
    STAGE_A(1, 0); STAGE_B(1, 0);
    VMW(6); SBAR();

#pragma unroll 1
    for (int t = 0; t < NT - 2; ++t) {
      const int k0 = ((t & 1) << 1), k1 = k0 | 1;
      { bf16x8 fa[4], fb[4]; G_RD(k0); STAGE_A(t + 1, 1); STAGE_B(t + 1, 1); VMW(6); LGKM0(); G_MM(); SBAR(); }
      { bf16x8 fa[4], fb[4]; G_RD(k1); STAGE_A(t + 2, 0); STAGE_B(t + 2, 0); VMW(6); LGKM0(); G_MM(); SBAR(); }
    }
    {  // t = NT-2
      const int k0 = (((NT - 2) & 1) << 1), k1 = k0 | 1;
      { bf16x8 fa[4], fb[4]; G_RD(k0); STAGE_A(NT - 1, 1); STAGE_B(NT - 1, 1); VMW(6); LGKM0(); G_MM(); SBAR(); }
      { bf16x8 fa[4], fb[4]; G_RD(k1);                                        VMW(3); LGKM0(); G_MM(); SBAR(); }
    }
    {  // t = NT-1
      const int k0 = (((NT - 1) & 1) << 1), k1 = k0 | 1;
      { bf16x8 fa[4], fb[4]; G_RD(k0);                                        VMW(0); LGKM0(); G_MM(); SBAR(); }
      { bf16x8 fa[4], fb[4]; G_RD(k1);                                                LGKM0(); G_MM(); SBAR(); }
    }

    // epilogue: C/D layout col=lane&15, row=(lane>>4)*4+reg
    const int segLo = csum[e], segHi = csum[e + 1];
#pragma unroll
    for (int mi = 0; mi < 4; ++mi) {
      const int rowb = r0 + wr * 64 + mi * 16 + ((lane >> 4) << 2);
#pragma unroll
      for (int ni = 0; ni < 4; ++ni) {
        const int col = c0 + wc * 64 + ni * 16 + l15;
#pragma unroll
        for (int r = 0; r < 4; ++r) {
          const int gr = rowb + r;
          if (gr >= segLo && gr < segHi) {
            if (FUSE) {
              float h = bf2f(f2bf(acc[mi][ni][r]));
              h = h > 0.f ? h : 0.f;
              OB[(size_t)gr * N + col] = f2bf(h * h);
            } else {
              OF[(size_t)gr * N + col] = bf2f(f2bf(acc[mi][ni][r]));
            }
          }
        }
      }
    }
#undef STAGE_A
#undef STAGE_B
#undef G_RD
#undef G_MM
  }
}

extern "C" void kernel_launch(void* const* d_in, const int* in_sizes, int n_in,
                              void* d_out, int out_size, void* d_ws, size_t ws_size,
                              hipStream_t stream) {
  const float* x = (const float*)d_in[0];
  const float* w_up = (const float*)d_in[1];
  const float* w_down = (const float*)d_in[2];
  const int* counts = (const int*)d_in[3];
  float* out = (float*)d_out;

  char* ws = (char*)d_ws;
  unsigned short* xb  = (unsigned short*)(ws);
  unsigned short* wub = (unsigned short*)(ws + (size_t)16 * 1024 * 1024);
  unsigned short* wdb = (unsigned short*)(ws + (size_t)48 * 1024 * 1024);
  unsigned short* hsq = (unsigned short*)(ws + (size_t)80 * 1024 * 1024);

  cvt_region<<<20480, 256, 0, stream>>>(x, w_up, w_down, xb, wub, wdb);
  // GEMM1: hsq = bf16(relu(bf16(x @ w_up^T))^2)  (T,H); grid 32 rb x 16 cb
  ggemm<D_DIM, H_DIM, true>
      <<<(T_TOKENS / 256) * (H_DIM / 128), 512, 0, stream>>>(xb, wub, counts, hsq, nullptr);
  // GEMM2: out = f32(bf16(hsq @ w_down^T))  (T,D); grid 32 rb x 8 cb
  ggemm<H_DIM, D_DIM, false>
      <<<(T_TOKENS / 256) * (D_DIM / 128), 512, 0, stream>>>(hsq, wdb, counts, nullptr, out);
}